// Round 4
// baseline (76.824 us; speedup 1.0000x reference)
//
#include <hip/hip_runtime.h>

// Problem constants (match reference)
#define IN_C   3
#define OUT_C  32
#define KS     5
#define B_N    16
#define H_N    64
#define W_N    64
#define NH     60
#define NW     60
#define PIX_PER_IMG (NH * NW)           // 3600
#define TOTAL_PIX   (B_N * PIX_PER_IMG) // 57600
#define ELEMS  (IN_C * KS * KS)         // 75
#define EPW    19                       // elems per wave (waves 0-2: 19, wave 3: 18)
#define ACC_STRIDE 65                   // bank = (o + lane) % 32 -> conflict-free reads

// Bins are a disjoint uniform partition of [-1,1]: each patch element p lands
// in exactly one bin o = floor((p-l0)/h) and contributes 16*(f*(1-f))^2 there.
//
// R4: single shared accumulator stripe per pixel, updated with fire-and-forget
// LDS float atomics (ds_add_f32, no dependent RMW chain). Block = 256 threads
// = 4 waves over 64 output pixels; lane <-> pixel, wave w handles patch
// elements [19w, min(75,19w+19)). Merge: wave w writes channels [8w,8w+8).
// Per-thread LDS instrs: 102 (R1) -> ~35; LDS 33.8KB -> 8.3KB.
__global__ __launch_bounds__(256) void local_conv_hist_kernel(
    const float* __restrict__ x,
    const float* __restrict__ lb,
    const float* __restrict__ rb,
    float* __restrict__ out) {

    __shared__ float acc[OUT_C * ACC_STRIDE];   // 32*65*4 = 8320 B
    const int t    = threadIdx.x;
    const int lane = t & 63;
    const int w    = t >> 6;

    // Cooperative zero: 2080 floats / 256 threads (9 strided passes, 2-way banks)
    for (int idx = t; idx < OUT_C * ACC_STRIDE; idx += 256) acc[idx] = 0.0f;
    __syncthreads();

    const int pix = blockIdx.x * 64 + lane;     // grid sized exactly: 900*64
    const int b   = pix / PIX_PER_IMG;
    const int rr  = pix % PIX_PER_IMG;
    const int oh  = rr / NW;
    const int ow  = rr % NW;

    const float l0    = lb[0];
    const float inv_h = 1.0f / (rb[0] - l0);

    const float* xb = x + (size_t)b * (IN_C * H_N * W_N) + oh * W_N + ow;

    const int e0 = w * EPW;
    const int e1 = (w == 3) ? ELEMS : (e0 + EPW);
#pragma unroll
    for (int k = 0; k < EPW; ++k) {
        const int e = e0 + k;
        if (e < e1) {                           // false only for wave 3's last iter
            const int c   = e / 25;
            const int rem = e % 25;
            const int i   = rem / 5;
            const int j   = rem % 5;
            const float p = xb[c * (H_N * W_N) + i * W_N + j];
            const float tt = (p - l0) * inv_h;
            if (tt > 0.0f && tt < (float)OUT_C) {
                const int   o = (int)tt;        // floor, since tt > 0
                const float f = tt - (float)o;
                const float v = f * (1.0f - f);
                atomicAdd(&acc[o * ACC_STRIDE + lane], v * v);  // ds_add_f32
            }
        }
    }

    __syncthreads();

    // Merge: wave w -> channels [8w, 8w+8), lane -> pixel. Reads conflict-free
    // (bank = (o+lane)%32, lanes consecutive); stores coalesced 256B.
    float* ob = out + (size_t)b * (OUT_C * PIX_PER_IMG) + rr;
#pragma unroll
    for (int k = 0; k < 8; ++k) {
        const int o = w * 8 + k;
        ob[o * PIX_PER_IMG] = 16.0f * acc[o * ACC_STRIDE + lane];
    }
}

extern "C" void kernel_launch(void* const* d_in, const int* in_sizes, int n_in,
                              void* d_out, int out_size, void* d_ws, size_t ws_size,
                              hipStream_t stream) {
    const float* x  = (const float*)d_in[0];
    const float* lb = (const float*)d_in[1];
    const float* rb = (const float*)d_in[2];
    float* out = (float*)d_out;

    const int grid = TOTAL_PIX / 64;    // 900 blocks x 256 threads
    local_conv_hist_kernel<<<grid, 256, 0, stream>>>(x, lb, rb, out);
}

// Round 5
// 66.086 us; speedup vs baseline: 1.1625x; 1.1625x over previous
//
#include <hip/hip_runtime.h>

// Problem constants (match reference)
#define IN_C   3
#define OUT_C  32
#define KS     5
#define B_N    16
#define H_N    64
#define W_N    64
#define NH     60
#define NW     60
#define PIX_PER_IMG (NH * NW)           // 3600
#define TOTAL_PIX   (B_N * PIX_PER_IMG) // 57600

// Bins are a disjoint uniform partition of [-1,1]: each patch element p lands
// in exactly one bin o = floor((p-l0)/h) and contributes 16*(f*(1-f))^2 there.
//
// R5 = R3 structure (best measured: private LDS stripes, plain writes,
// 4 waves x 64 pixels, stride-33 stripes) + fully static element lists:
// switch(w) dispatches to 4 unrolled bodies where (c,i,j) are compile-time
// constants -> no runtime div/mod (~150 VALU/thread saved), loads become
// base+immediate and pipeline back-to-back.
#define ELEM(c,i,j) do {                                        \
    const float p  = xb[(c)*(H_N*W_N) + (i)*W_N + (j)];         \
    const float tt = (p - l0) * inv_h;                          \
    if (tt > 0.0f && tt < (float)OUT_C) {                       \
        const int   o = (int)tt;        /* floor, tt > 0 */     \
        const float f = tt - (float)o;                          \
        const float v = f * (1.0f - f);                         \
        my[o] += v * v;                                         \
    } } while (0)

#define ROW5(c,i) do { ELEM(c,i,0); ELEM(c,i,1); ELEM(c,i,2); ELEM(c,i,3); ELEM(c,i,4); } while (0)

__global__ __launch_bounds__(256) void local_conv_hist_kernel(
    const float* __restrict__ x,
    const float* __restrict__ lb,
    const float* __restrict__ rb,
    float* __restrict__ out) {

    __shared__ float acc[256 * 33];     // 33,792 B -> 4 blocks/CU by LDS
    const int t    = threadIdx.x;
    const int lane = t & 63;
    const int w    = t >> 6;

    float* my = &acc[t * 33];
#pragma unroll
    for (int o = 0; o < OUT_C; ++o) my[o] = 0.0f;
    // no barrier needed before scatter: each thread touches only its own stripe

    const int pix = blockIdx.x * 64 + lane;     // grid sized exactly: 900*64
    const int b   = pix / PIX_PER_IMG;
    const int rr  = pix % PIX_PER_IMG;
    const int oh  = rr / NW;
    const int ow  = rr % NW;

    const float l0    = lb[0];
    const float inv_h = 1.0f / (rb[0] - l0);

    const float* xb = x + (size_t)b * (IN_C * H_N * W_N) + oh * W_N + ow;

    // Elements 0..74 = (c,i,j), e = c*25 + i*5 + j. Wave w owns e in
    // [19w, min(75, 19w+19)). Uniform branch per wave (scalar, no divergence).
    if (w == 0) {
        ROW5(0,0); ROW5(0,1); ROW5(0,2);
        ELEM(0,3,0); ELEM(0,3,1); ELEM(0,3,2); ELEM(0,3,3);          // 19
    } else if (w == 1) {
        ELEM(0,3,4); ROW5(0,4); ROW5(1,0); ROW5(1,1);
        ELEM(1,2,0); ELEM(1,2,1); ELEM(1,2,2);                       // 19
    } else if (w == 2) {
        ELEM(1,2,3); ELEM(1,2,4); ROW5(1,3); ROW5(1,4); ROW5(2,0);
        ELEM(2,1,0); ELEM(2,1,1);                                    // 19
    } else {
        ELEM(2,1,2); ELEM(2,1,3); ELEM(2,1,4);
        ROW5(2,2); ROW5(2,3); ROW5(2,4);                             // 18
    }

    __syncthreads();

    // Merge 4 stripes and write: wave w -> channels [8w, 8w+8), lane -> pixel.
    // LDS read bank = (lane + o) % 32: 2 lanes/bank (free). Stores coalesced.
    float* ob = out + (size_t)b * (OUT_C * PIX_PER_IMG) + rr;
#pragma unroll
    for (int k = 0; k < 8; ++k) {
        const int o = w * 8 + k;
        const float s = acc[(0 * 64 + lane) * 33 + o]
                      + acc[(1 * 64 + lane) * 33 + o]
                      + acc[(2 * 64 + lane) * 33 + o]
                      + acc[(3 * 64 + lane) * 33 + o];
        ob[o * PIX_PER_IMG] = 16.0f * s;
    }
}

extern "C" void kernel_launch(void* const* d_in, const int* in_sizes, int n_in,
                              void* d_out, int out_size, void* d_ws, size_t ws_size,
                              hipStream_t stream) {
    const float* x  = (const float*)d_in[0];
    const float* lb = (const float*)d_in[1];
    const float* rb = (const float*)d_in[2];
    float* out = (float*)d_out;

    const int grid = TOTAL_PIX / 64;    // 900 blocks x 256 threads
    local_conv_hist_kernel<<<grid, 256, 0, stream>>>(x, lb, rb, out);
}

// Round 6
// 65.980 us; speedup vs baseline: 1.1643x; 1.0016x over previous
//
#include <hip/hip_runtime.h>

// Problem constants (match reference)
#define IN_C   3
#define OUT_C  32
#define KS     5
#define B_N    16
#define H_N    64
#define W_N    64
#define NH     60
#define NW     60
#define PIX_PER_IMG (NH * NW)           // 3600
#define TOTAL_PIX   (B_N * PIX_PER_IMG) // 57600

// Bins are a disjoint uniform partition of [-1,1]: each patch element p lands
// in exactly one bin o = floor((p-l0)/h) and contributes 16*(f*(1-f))^2 there.
//
// R6 = R5 with 8-way element split: block = 512 threads = 8 waves over 64
// pixels. Each wave's serial LDS RMW chain drops 19 -> 9/10 links; occupancy
// 14 -> 16 waves/CU (2 blocks/CU at 67.6KB LDS). Static (c,i,j) lists per
// wave (no div/mod). Merge: wave w sums 8 stripes for channels [4w,4w+4)
// (channel-consecutive reads -> b128; bank = (lane+o)%32, conflict-free).
// NOTE (R4 lesson): ds_add_f32 LDS atomics are SLOW on gfx950 — plain
// RMW on private stripes beat them by ~10 us here.
#define ELEM(c,i,j) do {                                        \
    const float p  = xb[(c)*(H_N*W_N) + (i)*W_N + (j)];         \
    const float tt = (p - l0) * inv_h;                          \
    if (tt > 0.0f && tt < (float)OUT_C) {                       \
        const int   o = (int)tt;        /* floor, tt > 0 */     \
        const float f = tt - (float)o;                          \
        const float v = f * (1.0f - f);                         \
        my[o] += v * v;                                         \
    } } while (0)

#define ROW5(c,i) do { ELEM(c,i,0); ELEM(c,i,1); ELEM(c,i,2); ELEM(c,i,3); ELEM(c,i,4); } while (0)

__global__ __launch_bounds__(512) void local_conv_hist_kernel(
    const float* __restrict__ x,
    const float* __restrict__ lb,
    const float* __restrict__ rb,
    float* __restrict__ out) {

    __shared__ float acc[512 * 33];     // 67,584 B -> 2 blocks/CU (135KB < 160KB)
    const int t    = threadIdx.x;
    const int lane = t & 63;
    const int w    = t >> 6;            // 0..7

    float* my = &acc[t * 33];
#pragma unroll
    for (int o = 0; o < OUT_C; ++o) my[o] = 0.0f;
    // no barrier needed before scatter: each thread touches only its own stripe

    const int pix = blockIdx.x * 64 + lane;     // grid sized exactly: 900*64
    const int b   = pix / PIX_PER_IMG;
    const int rr  = pix % PIX_PER_IMG;
    const int oh  = rr / NW;
    const int ow  = rr % NW;

    const float l0    = lb[0];
    const float inv_h = 1.0f / (rb[0] - l0);

    const float* xb = x + (size_t)b * (IN_C * H_N * W_N) + oh * W_N + ow;

    // Elements 0..74 = (c,i,j), e = c*25 + i*5 + j.
    // w0-2: 10 elems each; w3-7: 9 elems each. Wave-uniform branch.
    if (w == 0) {
        ROW5(0,0); ROW5(0,1);                                       // e0-9
    } else if (w == 1) {
        ROW5(0,2); ROW5(0,3);                                       // e10-19
    } else if (w == 2) {
        ROW5(0,4); ROW5(1,0);                                       // e20-29
    } else if (w == 3) {
        ROW5(1,1); ELEM(1,2,0); ELEM(1,2,1); ELEM(1,2,2); ELEM(1,2,3); // e30-38
    } else if (w == 4) {
        ELEM(1,2,4); ROW5(1,3); ELEM(1,4,0); ELEM(1,4,1); ELEM(1,4,2); // e39-47
    } else if (w == 5) {
        ELEM(1,4,3); ELEM(1,4,4); ROW5(2,0); ELEM(2,1,0); ELEM(2,1,1); // e48-56
    } else if (w == 6) {
        ELEM(2,1,2); ELEM(2,1,3); ELEM(2,1,4); ROW5(2,2); ELEM(2,3,0); // e57-65
    } else {
        ELEM(2,3,1); ELEM(2,3,2); ELEM(2,3,3); ELEM(2,3,4); ROW5(2,4); // e66-74
    }

    __syncthreads();

    // Merge 8 stripes; wave w -> channels [4w, 4w+4), lane -> pixel.
    // For fixed stripe s the 4 channel slots are consecutive -> b128 reads.
    float* ob = out + (size_t)b * (OUT_C * PIX_PER_IMG) + rr;
#pragma unroll
    for (int k = 0; k < 4; ++k) {
        const int o = w * 4 + k;
        float s = 0.0f;
#pragma unroll
        for (int sv = 0; sv < 8; ++sv)
            s += acc[(sv * 64 + lane) * 33 + o];
        ob[o * PIX_PER_IMG] = 16.0f * s;
    }
}

extern "C" void kernel_launch(void* const* d_in, const int* in_sizes, int n_in,
                              void* d_out, int out_size, void* d_ws, size_t ws_size,
                              hipStream_t stream) {
    const float* x  = (const float*)d_in[0];
    const float* lb = (const float*)d_in[1];
    const float* rb = (const float*)d_in[2];
    float* out = (float*)d_out;

    const int grid = TOTAL_PIX / 64;    // 900 blocks x 512 threads
    local_conv_hist_kernel<<<grid, 512, 0, stream>>>(x, lb, rb, out);
}